// Round 1
// baseline (117.905 us; speedup 1.0000x reference)
//
#include <hip/hip_runtime.h>
#include <hip/hip_bf16.h>

// MFMA fragment types per cdna_hip_programming.md §3 (compile-verified form)
typedef short bf16x8 __attribute__((ext_vector_type(8)));
typedef float f32x4  __attribute__((ext_vector_type(4)));

#define ZD    128   // feature dim (fixed by problem)
#define WTILE 64    // per-wave output tile (64x64)

__device__ __forceinline__ unsigned short f2bf(float x) {
    // round-to-nearest-even fp32 -> bf16
    unsigned u = __float_as_uint(x);
    u = (u + 0x7FFFu + ((u >> 16) & 1u)) >> 16;
    return (unsigned short)u;
}

// ---------------------------------------------------------------------------
// Kernel A: class counts + row squared norms + fp32->bf16 conversion of z
// grid = N/64 blocks x 256 threads; each block owns 64 rows.
// ---------------------------------------------------------------------------
__global__ __launch_bounds__(256) void dep_prep(
    const float* __restrict__ z, const int* __restrict__ s,
    float* __restrict__ sq, unsigned short* __restrict__ zb,
    int* __restrict__ counts)
{
    const int wave = threadIdx.x >> 6;
    const int lane = threadIdx.x & 63;
    const int r0   = blockIdx.x * 64;

    if (wave == 0) {
        int sv = s[r0 + lane];
        #pragma unroll
        for (int c = 0; c < 4; ++c) {
            unsigned long long m = __ballot(sv == c);
            if (lane == 0) atomicAdd(&counts[c], __popcll(m));
        }
    }

    // each wave handles 16 rows: coalesced float2 per lane (64*8B = 512B/row)
    for (int it = 0; it < 16; ++it) {
        const int r = r0 + wave * 16 + it;
        const float2 v = ((const float2*)(z + (size_t)r * ZD))[lane];
        ushort2 u;
        u.x = f2bf(v.x);
        u.y = f2bf(v.y);
        ((ushort2*)(zb + (size_t)r * ZD))[lane] = u;
        float p = v.x * v.x + v.y * v.y;
        #pragma unroll
        for (int off = 32; off > 0; off >>= 1)
            p += __shfl_down(p, off, 64);
        if (lane == 0) sq[r] = p;
    }
}

// ---------------------------------------------------------------------------
// Kernel B: weighted pairwise-RBF reduction over the upper triangle of tiles.
// One wave per 64x64 tile: 4x4 grid of 16x16x32 bf16 MFMAs over K=128.
// Off-diagonal K_z entries are ~e^-128; only d2<80 enters the exp path
// (execz-skipped for virtually every wave). i==j excluded (added analytically
// in finalize to avoid bf16 breaking the sq_i - dot_ii cancellation).
// ---------------------------------------------------------------------------
__global__ __launch_bounds__(256) void dep_pair(
    const unsigned short* __restrict__ zb, const float* __restrict__ sq,
    const int* __restrict__ s, const int* __restrict__ counts,
    float* __restrict__ acc_out, int T, int ntasks, float invN)
{
    const int wave = threadIdx.x >> 6;
    const int lane = threadIdx.x & 63;
    const int t    = blockIdx.x * 4 + wave;
    if (t >= ntasks) return;

    // map linear t -> (ti <= tj) over T x T tile grid, row-major triangle
    #define TRI_BASE(x) ((x) * T - ((x) * ((x) - 1)) / 2)
    double disc = (2.0 * T + 1.0) * (2.0 * T + 1.0) - 8.0 * (double)t;
    int ti = (int)((2.0 * T + 1.0 - sqrt(disc)) * 0.5);
    if (ti < 0) ti = 0;
    if (ti > T - 1) ti = T - 1;
    while (ti + 1 < T && TRI_BASE(ti + 1) <= t) ++ti;
    while (ti > 0 && TRI_BASE(ti) > t) --ti;
    const int tj = ti + (t - TRI_BASE(ti));
    #undef TRI_BASE

    const int i0 = ti * WTILE;
    const int j0 = tj * WTILE;

    const int l15  = lane & 15;
    const int quad = lane >> 4;

    // A-frag: A[m=lane&15][k=quad*8+j]; B-frag identical layout for z*z^T
    const unsigned short* abase = zb + (size_t)(i0 + l15) * ZD + quad * 8;
    const unsigned short* bbase = zb + (size_t)(j0 + l15) * ZD + quad * 8;

    f32x4 accv[4][4];
    #pragma unroll
    for (int a = 0; a < 4; ++a)
        #pragma unroll
        for (int b = 0; b < 4; ++b)
            accv[a][b] = (f32x4){0.f, 0.f, 0.f, 0.f};

    #pragma unroll
    for (int kc = 0; kc < 4; ++kc) {
        bf16x8 af[4], bfr[4];
        #pragma unroll
        for (int it = 0; it < 4; ++it)
            af[it] = *(const bf16x8*)(abase + it * 16 * ZD + kc * 32);
        #pragma unroll
        for (int jt = 0; jt < 4; ++jt)
            bfr[jt] = *(const bf16x8*)(bbase + jt * 16 * ZD + kc * 32);
        #pragma unroll
        for (int it = 0; it < 4; ++it)
            #pragma unroll
            for (int jt = 0; jt < 4; ++jt)
                accv[it][jt] = __builtin_amdgcn_mfma_f32_16x16x32_bf16(
                    af[it], bfr[jt], accv[it][jt], 0, 0, 0);
    }

    // class priors (uniform scalar loads)
    float p[4];
    #pragma unroll
    for (int c = 0; c < 4; ++c) p[c] = (float)counts[c] * invN;
    const float sump2 = p[0]*p[0] + p[1]*p[1] + p[2]*p[2] + p[3]*p[3];

    float sqj[4];
    #pragma unroll
    for (int jt = 0; jt < 4; ++jt) sqj[jt] = sq[j0 + jt * 16 + l15];

    float local = 0.f;
    #pragma unroll
    for (int it = 0; it < 4; ++it) {
        #pragma unroll
        for (int r = 0; r < 4; ++r) {
            const int i = i0 + it * 16 + quad * 4 + r;   // C/D: row=quad*4+reg
            const float sqi = sq[i];
            #pragma unroll
            for (int jt = 0; jt < 4; ++jt) {
                const int j = j0 + jt * 16 + l15;        // C/D: col=lane&15
                float d2 = sqi + sqj[jt] - 2.0f * accv[it][jt][r];
                d2 = fmaxf(d2, 0.0f);
                if (d2 < 80.0f && i != j) {
                    // exp(-40) ~ 4e-18: skipped mass is invisible at fp32
                    const int si = s[i], sj = s[j];
                    const float w = (si == sj ? 1.0f : 0.0f)
                                  - p[si] - p[sj] + sump2;
                    local += w * __expf(-0.5f * d2);
                }
            }
        }
    }
    if (ti < tj) local *= 2.0f;   // off-diagonal tiles count both (i,j),(j,i)

    #pragma unroll
    for (int off = 32; off > 0; off >>= 1)
        local += __shfl_down(local, off, 64);
    if (lane == 0 && local != 0.0f)
        atomicAdd(acc_out, local);
}

// ---------------------------------------------------------------------------
// Kernel C: analytic diagonal + scaling.
// diag = sum_i w(s_i,s_i)*K_z[i,i] = n - (sum_c n_c^2)/n   (K_z[i,i] ~= 1)
// ---------------------------------------------------------------------------
__global__ __launch_bounds__(64) void dep_finalize(
    const float* __restrict__ acc, const int* __restrict__ counts,
    const float* __restrict__ norm, float* __restrict__ out, int N)
{
    if (threadIdx.x == 0) {
        double n  = (double)N;
        double c2 = 0.0;
        for (int c = 0; c < 4; ++c)
            c2 += (double)counts[c] * (double)counts[c];
        double diag  = n - c2 / n;
        double total = ((double)acc[0] + diag) * (1.0 - exp(-1.0));
        out[0] = (float)(total / ((double)norm[0] * n * n));
    }
}

extern "C" void kernel_launch(void* const* d_in, const int* in_sizes, int n_in,
                              void* d_out, int out_size, void* d_ws, size_t ws_size,
                              hipStream_t stream)
{
    const float* z    = (const float*)d_in[0];
    const int*   s    = (const int*)d_in[1];
    const float* norm = (const float*)d_in[2];
    float* out = (float*)d_out;

    const int N = in_sizes[1];     // 8192 samples
    const int T = N / WTILE;       // 128 tiles per dim

    char* ws = (char*)d_ws;
    float* acc    = (float*)ws;                                   // [0,4)
    int*   counts = (int*)(ws + 16);                              // [16,32)
    float* sq     = (float*)(ws + 64);                            // N floats
    unsigned short* zb = (unsigned short*)(ws + 64 + (size_t)N * sizeof(float)); // N*ZD bf16 (16B-aligned)

    hipMemsetAsync(d_ws, 0, 64, stream);                          // acc + counts
    dep_prep<<<N / 64, 256, 0, stream>>>(z, s, sq, zb, counts);

    const int ntasks = T * (T + 1) / 2;                           // 8256
    dep_pair<<<(ntasks + 3) / 4, 256, 0, stream>>>(zb, sq, s, counts, acc,
                                                   T, ntasks, 1.0f / (float)N);
    dep_finalize<<<1, 64, 0, stream>>>(acc, counts, norm, out, N);
}

// Round 2
// 87.110 us; speedup vs baseline: 1.3535x; 1.3535x over previous
//
#include <hip/hip_runtime.h>
#include <hip/hip_bf16.h>

typedef short bf16x8 __attribute__((ext_vector_type(8)));
typedef float f32x4  __attribute__((ext_vector_type(4)));

#define ZD      128      // feature dim
#define BT      128      // block tile (128x128 per block, 64x64 per wave)
#define D2_CUT  60.0f    // exact-path cutoff: exp(-30)~9e-14, sum budget ~78
#define D2_TRIG 62.0f    // conservative trigger (2.0 margin > any bf16 dot err)

__device__ __forceinline__ unsigned short f2bf(float x) {
    unsigned u = __float_as_uint(x);
    u = (u + 0x7FFFu + ((u >> 16) & 1u)) >> 16;
    return (unsigned short)u;
}

// ---------------------------------------------------------------------------
// Kernel A: per-row ||z||^2 (fp32), per-64-row-group min(||z||^2), z->bf16,
// class counts. 128 blocks x 256 threads; block owns 64 rows.
// Loads: wave covers 2 rows/iter as contiguous 1KB float4; partial dot4s go
// through an LDS transpose (pad 33) so there is NO serial shuffle chain.
// ---------------------------------------------------------------------------
__global__ __launch_bounds__(256) void dep_prep(
    const float* __restrict__ z, const int* __restrict__ s,
    float* __restrict__ sq, float* __restrict__ sqmin,
    unsigned short* __restrict__ zb, int* __restrict__ counts)
{
    __shared__ float part[64][33];
    const int tid  = threadIdx.x;
    const int wave = tid >> 6, lane = tid & 63;
    const int half = lane >> 5, c = lane & 31;
    const int r0   = blockIdx.x * 64;

    if (wave == 0) {
        int sv = s[r0 + lane];
        #pragma unroll
        for (int cl = 0; cl < 4; ++cl) {
            unsigned long long m = __ballot(sv == cl);
            if (lane == 0) atomicAdd(&counts[cl], __popcll(m));
        }
    }

    #pragma unroll
    for (int i = 0; i < 8; ++i) {
        const int rloc = wave * 16 + i * 2 + half;   // row within block
        const int r    = r0 + rloc;
        float4 v = ((const float4*)z)[r * 32 + c];
        ushort4 u;
        u.x = f2bf(v.x); u.y = f2bf(v.y); u.z = f2bf(v.z); u.w = f2bf(v.w);
        ((ushort4*)zb)[r * 32 + c] = u;
        part[rloc][c] = v.x*v.x + v.y*v.y + v.z*v.z + v.w*v.w;
    }
    __syncthreads();

    if (wave == 0) {
        float sum = 0.f;
        #pragma unroll
        for (int k = 0; k < 32; ++k) sum += part[lane][k];   // bank (lane+k)%32: free
        sq[r0 + lane] = sum;
        float mn = sum;
        #pragma unroll
        for (int off = 1; off < 64; off <<= 1)
            mn = fminf(mn, __shfl_xor(mn, off, 64));
        if (lane == 0) sqmin[blockIdx.x] = mn;
    }
}

// ---------------------------------------------------------------------------
// Kernel B: one block per 128x128 tile of the upper triangle (T=64, 2080
// blocks). Stage A/B panels (64KB) into LDS with 16B-chunk XOR swizzle
// (chunk ^= row&15) -> both ds_write_b128 and the MFMA-fragment
// ds_read_b128 patterns are bank-uniform. Each wave: 64x64 quadrant,
// 64 x mfma_f32_16x16x32_bf16. Epilogue: wave-max of dots vs the
// conservative bound sqmin_A+sqmin_B-2*max < D2_TRIG; exact slow path only
// when it fires (diag-quadrant waves + ~1e-3 of the rest).
// ---------------------------------------------------------------------------
__global__ __launch_bounds__(256, 2) void dep_pair(
    const unsigned short* __restrict__ zb, const float* __restrict__ sq,
    const float* __restrict__ sqmin, const int* __restrict__ s,
    const int* __restrict__ counts, float* __restrict__ acc_out,
    int T, float invN)
{
    __shared__ unsigned short Apan[BT * ZD];   // 32KB
    __shared__ unsigned short Bpan[BT * ZD];   // 32KB

    const int tid = threadIdx.x;

    // block-uniform triangle map t -> (ti <= tj)
    const int t = blockIdx.x;
    #define TRI_BASE(x) ((x) * T - ((x) * ((x) - 1)) / 2)
    double disc = (2.0 * T + 1.0) * (2.0 * T + 1.0) - 8.0 * (double)t;
    int ti = (int)((2.0 * T + 1.0 - sqrt(disc)) * 0.5);
    if (ti < 0) ti = 0;
    if (ti > T - 1) ti = T - 1;
    while (ti + 1 < T && TRI_BASE(ti + 1) <= t) ++ti;
    while (ti > 0 && TRI_BASE(ti) > t) --ti;
    const int tj = ti + (t - TRI_BASE(ti));
    #undef TRI_BASE

    const int i0 = ti * BT, j0 = tj * BT;

    // stage both panels: coalesced 16B chunks, swizzled LDS placement
    #pragma unroll
    for (int i = 0; i < 8; ++i) {
        const int L   = i * 256 + tid;        // chunk index in panel [0,2048)
        const int row = L >> 4, ch = L & 15;
        const int dst = row * ZD + (((ch ^ (row & 15)) << 3));
        uint4 a = ((const uint4*)(zb + (size_t)i0 * ZD))[L];
        uint4 b = ((const uint4*)(zb + (size_t)j0 * ZD))[L];
        *(uint4*)(Apan + dst) = a;
        *(uint4*)(Bpan + dst) = b;
    }
    __syncthreads();

    const int wave = tid >> 6, lane = tid & 63;
    const int wi = wave >> 1, wj = wave & 1;     // 64x64 quadrant
    const int l15 = lane & 15, quad = lane >> 4;

    f32x4 accv[4][4];
    #pragma unroll
    for (int a = 0; a < 4; ++a)
        #pragma unroll
        for (int b = 0; b < 4; ++b)
            accv[a][b] = (f32x4){0.f, 0.f, 0.f, 0.f};

    #pragma unroll
    for (int kc = 0; kc < 4; ++kc) {
        bf16x8 af[4], bfr[4];
        #pragma unroll
        for (int it = 0; it < 4; ++it) {
            const int row = wi * 64 + it * 16 + l15;
            const int ch  = (quad + 4 * kc) ^ l15;     // row&15 == l15
            af[it] = *(const bf16x8*)(Apan + row * ZD + (ch << 3));
        }
        #pragma unroll
        for (int jt = 0; jt < 4; ++jt) {
            const int row = wj * 64 + jt * 16 + l15;
            const int ch  = (quad + 4 * kc) ^ l15;
            bfr[jt] = *(const bf16x8*)(Bpan + row * ZD + (ch << 3));
        }
        #pragma unroll
        for (int it = 0; it < 4; ++it)
            #pragma unroll
            for (int jt = 0; jt < 4; ++jt)
                accv[it][jt] = __builtin_amdgcn_mfma_f32_16x16x32_bf16(
                    af[it], bfr[jt], accv[it][jt], 0, 0, 0);
    }

    // ---- fast epilogue: wave-max of dots vs conservative d2 lower bound ----
    float m = -1e30f;
    #pragma unroll
    for (int it = 0; it < 4; ++it)
        #pragma unroll
        for (int jt = 0; jt < 4; ++jt) {
            const f32x4 v = accv[it][jt];
            m = fmaxf(m, fmaxf(fmaxf(v[0], v[1]), fmaxf(v[2], v[3])));
        }
    #pragma unroll
    for (int off = 1; off < 64; off <<= 1)
        m = fmaxf(m, __shfl_xor(m, off, 64));

    const int gA = ti * 2 + wi, gB = tj * 2 + wj;   // 64-row groups
    const float bound = sqmin[gA] + sqmin[gB] - 2.0f * m;

    if (bound < D2_TRIG) {   // wave-uniform branch; rare except i==j quadrants
        float p[4];
        #pragma unroll
        for (int cl = 0; cl < 4; ++cl) p[cl] = (float)counts[cl] * invN;
        const float sump2 = p[0]*p[0] + p[1]*p[1] + p[2]*p[2] + p[3]*p[3];

        const int ibase = i0 + wi * 64, jbase = j0 + wj * 64;
        float sqj[4];
        #pragma unroll
        for (int jt = 0; jt < 4; ++jt) sqj[jt] = sq[jbase + jt * 16 + l15];

        float local = 0.f;
        #pragma unroll
        for (int it = 0; it < 4; ++it) {
            #pragma unroll
            for (int r = 0; r < 4; ++r) {
                const int i = ibase + it * 16 + quad * 4 + r;  // C/D row=quad*4+reg
                const float sqi = sq[i];
                #pragma unroll
                for (int jt = 0; jt < 4; ++jt) {
                    const int j = jbase + jt * 16 + l15;       // C/D col=lane&15
                    float d2 = sqi + sqj[jt] - 2.0f * accv[it][jt][r];
                    d2 = fmaxf(d2, 0.0f);
                    if (d2 < D2_CUT && i != j) {
                        const int si = s[i], sj = s[j];
                        const float w = (si == sj ? 1.0f : 0.0f)
                                      - p[si] - p[sj] + sump2;
                        local += w * __expf(-0.5f * d2);
                    }
                }
            }
        }
        if (ti < tj) local *= 2.0f;   // off-diagonal blocks count both orders

        #pragma unroll
        for (int off = 32; off > 0; off >>= 1)
            local += __shfl_down(local, off, 64);
        if (lane == 0 && local != 0.0f)
            atomicAdd(acc_out, local);
    }
}

// ---------------------------------------------------------------------------
// Kernel C: analytic diagonal (K_z[i,i]=1) + scaling.
// ---------------------------------------------------------------------------
__global__ __launch_bounds__(64) void dep_finalize(
    const float* __restrict__ acc, const int* __restrict__ counts,
    const float* __restrict__ norm, float* __restrict__ out, int N)
{
    if (threadIdx.x == 0) {
        double n  = (double)N;
        double c2 = 0.0;
        for (int cl = 0; cl < 4; ++cl)
            c2 += (double)counts[cl] * (double)counts[cl];
        double diag  = n - c2 / n;
        double total = ((double)acc[0] + diag) * (1.0 - exp(-1.0));
        out[0] = (float)(total / ((double)norm[0] * n * n));
    }
}

extern "C" void kernel_launch(void* const* d_in, const int* in_sizes, int n_in,
                              void* d_out, int out_size, void* d_ws, size_t ws_size,
                              hipStream_t stream)
{
    const float* z    = (const float*)d_in[0];
    const int*   s    = (const int*)d_in[1];
    const float* norm = (const float*)d_in[2];
    float* out = (float*)d_out;

    const int N = in_sizes[1];     // 8192
    const int T = N / BT;          // 64 block-tiles per dim

    char* ws = (char*)d_ws;
    float* acc    = (float*)ws;                                   // [0,4)
    int*   counts = (int*)(ws + 16);                              // [16,32)
    float* sq     = (float*)(ws + 64);                            // N floats
    float* sqmin  = (float*)(ws + 64 + (size_t)N * 4);            // N/64 floats
    unsigned short* zb =
        (unsigned short*)(ws + 64 + (size_t)N * 4 + (size_t)(N / 64) * 4 + 48);

    hipMemsetAsync(d_ws, 0, 64, stream);                          // acc + counts
    dep_prep<<<N / 64, 256, 0, stream>>>(z, s, sq, sqmin, zb, counts);

    const int nblocks = T * (T + 1) / 2;                          // 2080
    dep_pair<<<nblocks, 256, 0, stream>>>(zb, sq, sqmin, s, counts, acc,
                                          T, 1.0f / (float)N);
    dep_finalize<<<1, 64, 0, stream>>>(acc, counts, norm, out, N);
}